// Round 6
// baseline (721.206 us; speedup 1.0000x reference)
//
#include <hip/hip_runtime.h>
#include <math.h>

#define Bn 4
#define Vn 5
#define Cc 32
#define Hh 256
#define Ww 320
#define DD 4
#define GG 8
#define HW (Hh*Ww)
#define BLOCKS_PER_B (HW/256)    // 320 pixel-blocks per image
#define NXCD 8
#define BAND (Bn * BLOCKS_PER_B / NXCD)   // 160 pixel-blocks per XCD band
#define NCHUNK 4

// ws layout: [0,768) P12 ; [1024, 1024+4*4*HW*32*4) channel-last features
#define FT_OFFSET 1024
#define FT_BYTES ((size_t)Bn * 4 * HW * 32 * 4)

// ---------------------------------------------------------------------------
// Prologue 1: per (b, src_view i=1..4) compute P = src_proj_new @ inv(ref_proj_new)
// ---------------------------------------------------------------------------
__global__ void proj_kernel(const float* __restrict__ proj, float* __restrict__ out12) {
    int t = blockIdx.x * blockDim.x + threadIdx.x;
    if (t >= Bn * (Vn - 1)) return;
    int b = t / (Vn - 1);
    int i = t % (Vn - 1) + 1;

    const float* pb = proj + (size_t)b * Vn * 2 * 16;

    double refm[16], srcm[16];
    {
        const float* E = pb + 0 * 32 + 0;
        const float* K = pb + 0 * 32 + 16;
        for (int r = 0; r < 3; r++)
            for (int c = 0; c < 4; c++) {
                double s = 0.0;
                for (int k = 0; k < 3; k++) s += (double)K[r*4+k] * (double)E[k*4+c];
                refm[r*4+c] = s;
            }
        for (int c = 0; c < 4; c++) refm[12+c] = (double)E[12+c];
    }
    {
        const float* E = pb + i * 32 + 0;
        const float* K = pb + i * 32 + 16;
        for (int r = 0; r < 3; r++)
            for (int c = 0; c < 4; c++) {
                double s = 0.0;
                for (int k = 0; k < 3; k++) s += (double)K[r*4+k] * (double)E[k*4+c];
                srcm[r*4+c] = s;
            }
        for (int c = 0; c < 4; c++) srcm[12+c] = (double)E[12+c];
    }

    double a[16], inv[16];
    for (int k = 0; k < 16; k++) { a[k] = refm[k]; inv[k] = 0.0; }
    inv[0] = inv[5] = inv[10] = inv[15] = 1.0;
    for (int col = 0; col < 4; col++) {
        int piv = col; double best = fabs(a[col*4+col]);
        for (int r = col + 1; r < 4; r++) {
            double v = fabs(a[r*4+col]);
            if (v > best) { best = v; piv = r; }
        }
        if (piv != col) {
            for (int c = 0; c < 4; c++) {
                double tmp = a[col*4+c]; a[col*4+c] = a[piv*4+c]; a[piv*4+c] = tmp;
                tmp = inv[col*4+c]; inv[col*4+c] = inv[piv*4+c]; inv[piv*4+c] = tmp;
            }
        }
        double rd = 1.0 / a[col*4+col];
        for (int c = 0; c < 4; c++) { a[col*4+c] *= rd; inv[col*4+c] *= rd; }
        for (int r = 0; r < 4; r++) {
            if (r == col) continue;
            double f = a[r*4+col];
            for (int c = 0; c < 4; c++) { a[r*4+c] -= f * a[col*4+c]; inv[r*4+c] -= f * inv[col*4+c]; }
        }
    }

    double P[16];
    for (int r = 0; r < 4; r++)
        for (int c = 0; c < 4; c++) {
            double s = 0.0;
            for (int k = 0; k < 4; k++) s += srcm[r*4+k] * inv[k*4+c];
            P[r*4+c] = s;
        }

    float* o = out12 + t * 12;
    o[0] = (float)P[0];  o[1] = (float)P[1];  o[2]  = (float)P[2];
    o[3] = (float)P[4];  o[4] = (float)P[5];  o[5]  = (float)P[6];
    o[6] = (float)P[8];  o[7] = (float)P[9];  o[8]  = (float)P[10];
    o[9] = (float)P[3];  o[10] = (float)P[7]; o[11] = (float)P[11];
}

// ---------------------------------------------------------------------------
// Prologue 2: repack src views (v=1..4) to channel-last: ft[b][v-1][pix][c].
// One thread per (b,v,pix): 32 coalesced strided reads -> 8 contiguous
// dwordx4 writes (128 B per pixel). ~336 MB coalesced => ~55 us.
// The 168 MB result fits in the 256 MB L3.
// ---------------------------------------------------------------------------
__global__ __launch_bounds__(256) void transpose_kernel(
    const float* __restrict__ features, float* __restrict__ ft)
{
    int t   = blockIdx.x * 256 + threadIdx.x;   // 0 .. Bn*4*HW-1
    int b   = t / (4 * HW);
    int r   = t - b * 4 * HW;
    int v   = r / HW;                            // 0..3 -> src view v+1
    int pix = r - v * HW;

    const float* src = features + ((size_t)(b * Vn + (v + 1)) * Cc) * HW + pix;
    float* dst = ft + (size_t)t * 32;

    #pragma unroll
    for (int q = 0; q < 8; q++) {
        float4 o;
        o.x = src[(size_t)(q * 4 + 0) * HW];
        o.y = src[(size_t)(q * 4 + 1) * HW];
        o.z = src[(size_t)(q * 4 + 2) * HW];
        o.w = src[(size_t)(q * 4 + 3) * HW];
        *reinterpret_cast<float4*>(dst + q * 4) = o;
    }
}

// ---------------------------------------------------------------------------
// Main kernel (transposed path). Diagnosis r0/r3/r5: dur invariant at
// ~300 us across FETCH 688->108 MB, occupancy 51<->83%, grid 1280<->5120.
// The invariant: ~40,960 vmem gather wave-instrs per CU; 720K cyc wall
// => ~17.6 cyc/instr = TA address-processing rate (4 addr/cyc, 64 lanes).
// The kernel is vmem-INSTRUCTION-issue bound.
//
// Fix: channel-last src layout -> each bilinear corner feeds 4 channels per
// dwordx4 -> per (i,d): 8 gathers instead of 32 -> per-thread 512 instead of
// 2048 -> TA time ~164K cyc. All 32 channels back in one thread (1280-block
// r3 grid + XCD banding, nontemporal stores kept).
// Corner bases are 128B-aligned (32 floats/pixel), +q*16B -> float4 legal.
// ---------------------------------------------------------------------------
__global__ __launch_bounds__(256) void cost_kernel_t(
    const float* __restrict__ depth_values,
    const float* __restrict__ features,
    const float* __restrict__ ft,
    const float* __restrict__ depth_interval,
    const float* __restrict__ view_weights,
    const float* __restrict__ P12,
    float* __restrict__ sim_out,
    float* __restrict__ samp_out)
{
    int bid  = blockIdx.x;               // 0..1279
    int xcd  = bid & (NXCD - 1);
    int s    = bid >> 3;
    int unit = xcd * BAND + s;
    int b    = unit / BLOCKS_PER_B;      // wave-uniform
    int pb   = unit - b * BLOCKS_PER_B;
    int pix  = pb * 256 + threadIdx.x;
    int h    = pix / Ww;
    int w    = pix - h * Ww;

    float inv_d = 1.0f / depth_values[b * HW + pix];
    float itv   = depth_interval[b * HW + pix];
    float dmin  = inv_d - 2.0f * itv;
    float step  = (4.0f * itv) / 3.0f;

    float depth[DD];
    #pragma unroll
    for (int d = 0; d < DD; d++) {
        float sdi = dmin + (float)d * step;
        depth[d] = 1.0f / sdi;
        __builtin_nontemporal_store(depth[d],
            &samp_out[((size_t)b * DD + d) * HW + pix]);
    }

    float vw[Vn - 1];
    float wsum = 0.0f;
    #pragma unroll
    for (int i = 0; i < Vn - 1; i++) {
        vw[i] = view_weights[((size_t)b * (Vn - 1) + i) * HW + pix];
        wsum += vw[i];
    }
    float dn = 1.0f / (wsum + 1e-6f);

    const float xf = (float)w, yf = (float)h;
    const float* refp = features + (size_t)b * Vn * Cc * HW + pix;
    float* so_base = sim_out + (size_t)b * (GG * DD) * HW + pix;

    float ref32[32];
    #pragma unroll
    for (int c = 0; c < 32; c++) ref32[c] = refp[(size_t)c * HW];

    float acc[GG][DD];
    #pragma unroll
    for (int g = 0; g < GG; g++)
        #pragma unroll
        for (int d = 0; d < DD; d++) acc[g][d] = 0.0f;

    #pragma unroll 1
    for (int i = 0; i < Vn - 1; i++) {
        const float* P = P12 + (b * (Vn - 1) + i) * 12;   // uniform -> s_load
        float rx = P[0] * xf + P[1] * yf + P[2];
        float ry = P[3] * xf + P[4] * yf + P[5];
        float rz = P[6] * xf + P[7] * yf + P[8];
        float tx = P[9], ty = P[10], tz = P[11];

        float scale = 0.25f * vw[i];
        const float* src = ft + ((size_t)(b * 4 + i) * HW) * 32;  // pixel-major

        #pragma unroll
        for (int d = 0; d < DD; d++) {
            float D  = depth[d];
            float px = rx * D + tx;
            float py = ry * D + ty;
            float pz = rz * D + tz;
            float rpz = 1.0f / pz;
            float gx = px * rpz;
            float gy = py * rpz;

            float x0f = floorf(gx);
            float y0f = floorf(gy);
            float wx1 = gx - x0f;
            float wy1 = gy - y0f;
            float wx0 = 1.0f - wx1;
            float wy0 = 1.0f - wy1;

            float xbf = fminf(fmaxf(x0f, 0.0f), (float)(Ww - 2));
            float ybf = fminf(fmaxf(y0f, 0.0f), (float)(Hh - 2));
            float dxf = x0f - xbf;
            float dyf = y0f - ybf;

            float pcx0 = (dxf == 0.0f) ? wx0 : ((dxf == -1.0f) ? wx1 : 0.0f);
            float pcx1 = (dxf == 0.0f) ? wx1 : ((dxf ==  1.0f) ? wx0 : 0.0f);
            float pcy0 = (dyf == 0.0f) ? wy0 : ((dyf == -1.0f) ? wy1 : 0.0f);
            float pcy1 = (dyf == 0.0f) ? wy1 : ((dyf ==  1.0f) ? wy0 : 0.0f);

            float W00 = pcx0 * pcy0 * scale;
            float W10 = pcx1 * pcy0 * scale;
            float W01 = pcx0 * pcy1 * scale;
            float W11 = pcx1 * pcy1 * scale;

            int o00 = (int)ybf * Ww + (int)xbf;
            const float* p00 = src + (size_t)o00 * 32;

            #pragma unroll
            for (int q = 0; q < GG; q++) {
                float4 A = *reinterpret_cast<const float4*>(p00 + q * 4);
                float4 Bq = *reinterpret_cast<const float4*>(p00 + 32 + q * 4);
                float4 Cq = *reinterpret_cast<const float4*>(p00 + Ww * 32 + q * 4);
                float4 Dq = *reinterpret_cast<const float4*>(p00 + Ww * 32 + 32 + q * 4);
                float v0 = W00 * A.x + W10 * Bq.x + W01 * Cq.x + W11 * Dq.x;
                float v1 = W00 * A.y + W10 * Bq.y + W01 * Cq.y + W11 * Dq.y;
                float v2 = W00 * A.z + W10 * Bq.z + W01 * Cq.z + W11 * Dq.z;
                float v3 = W00 * A.w + W10 * Bq.w + W01 * Cq.w + W11 * Dq.w;
                acc[q][d] += v0 * ref32[q*4+0] + v1 * ref32[q*4+1]
                           + v2 * ref32[q*4+2] + v3 * ref32[q*4+3];
            }
        }
    }

    #pragma unroll
    for (int g = 0; g < GG; g++)
        #pragma unroll
        for (int d = 0; d < DD; d++)
            __builtin_nontemporal_store(acc[g][d] * dn,
                &so_base[(size_t)(g * DD + d) * HW]);
}

// ---------------------------------------------------------------------------
// Fallback (= verified round-5 kernel, 300 us) used when ws_size can't hold
// the repacked features. Chunk-split grid, XCD banding, nontemporal stores.
// ---------------------------------------------------------------------------
__global__ __launch_bounds__(256) void cost_kernel_fb(
    const float* __restrict__ depth_values,
    const float* __restrict__ features,
    const float* __restrict__ depth_interval,
    const float* __restrict__ view_weights,
    const float* __restrict__ P12,
    float* __restrict__ sim_out,
    float* __restrict__ samp_out)
{
    int bid   = blockIdx.x;
    int xcd   = bid & (NXCD - 1);
    int s     = bid >> 3;
    int pbb   = s >> 2;
    int chunk = s & 3;
    int unit  = xcd * BAND + pbb;
    int b     = unit / BLOCKS_PER_B;
    int pb    = unit - b * BLOCKS_PER_B;
    int c0    = chunk * 8;

    int pix = pb * 256 + threadIdx.x;
    int h   = pix / Ww;
    int w   = pix - h * Ww;

    float inv_d = 1.0f / depth_values[b * HW + pix];
    float itv   = depth_interval[b * HW + pix];
    float dmin  = inv_d - 2.0f * itv;
    float step  = (4.0f * itv) / 3.0f;

    float depth[DD];
    #pragma unroll
    for (int d = 0; d < DD; d++) {
        float sdi = dmin + (float)d * step;
        depth[d] = 1.0f / sdi;
    }
    if (chunk == 0) {
        #pragma unroll
        for (int d = 0; d < DD; d++)
            __builtin_nontemporal_store(depth[d],
                &samp_out[((size_t)b * DD + d) * HW + pix]);
    }

    float vw[Vn - 1];
    float wsum = 0.0f;
    #pragma unroll
    for (int i = 0; i < Vn - 1; i++) {
        vw[i] = view_weights[((size_t)b * (Vn - 1) + i) * HW + pix];
        wsum += vw[i];
    }
    float dn = 1.0f / (wsum + 1e-6f);

    const float xf = (float)w, yf = (float)h;
    const float* refp = features + (size_t)b * Vn * Cc * HW + pix;
    float* so_base = sim_out + (size_t)b * (GG * DD) * HW + pix;

    float ref8[8];
    #pragma unroll
    for (int j = 0; j < 8; j++) ref8[j] = refp[(size_t)(c0 + j) * HW];

    float acc[2][DD];
    #pragma unroll
    for (int g2 = 0; g2 < 2; g2++)
        #pragma unroll
        for (int d = 0; d < DD; d++) acc[g2][d] = 0.0f;

    #pragma unroll 1
    for (int i = 0; i < Vn - 1; i++) {
        const float* P = P12 + (b * (Vn - 1) + i) * 12;
        float rx = P[0] * xf + P[1] * yf + P[2];
        float ry = P[3] * xf + P[4] * yf + P[5];
        float rz = P[6] * xf + P[7] * yf + P[8];
        float tx = P[9], ty = P[10], tz = P[11];

        float scale = 0.25f * vw[i];
        const float* src = features + ((size_t)(b * Vn) + (i + 1)) * Cc * HW
                         + (size_t)c0 * HW;

        #pragma unroll
        for (int d = 0; d < DD; d++) {
            float D  = depth[d];
            float px = rx * D + tx;
            float py = ry * D + ty;
            float pz = rz * D + tz;
            float rpz = 1.0f / pz;
            float gx = px * rpz;
            float gy = py * rpz;

            float x0f = floorf(gx);
            float y0f = floorf(gy);
            float wx1 = gx - x0f;
            float wy1 = gy - y0f;
            float wx0 = 1.0f - wx1;
            float wy0 = 1.0f - wy1;

            float xbf = fminf(fmaxf(x0f, 0.0f), (float)(Ww - 2));
            float ybf = fminf(fmaxf(y0f, 0.0f), (float)(Hh - 2));
            float dxf = x0f - xbf;
            float dyf = y0f - ybf;

            float pcx0 = (dxf == 0.0f) ? wx0 : ((dxf == -1.0f) ? wx1 : 0.0f);
            float pcx1 = (dxf == 0.0f) ? wx1 : ((dxf ==  1.0f) ? wx0 : 0.0f);
            float pcy0 = (dyf == 0.0f) ? wy0 : ((dyf == -1.0f) ? wy1 : 0.0f);
            float pcy1 = (dyf == 0.0f) ? wy1 : ((dyf ==  1.0f) ? wy0 : 0.0f);

            float W00 = pcx0 * pcy0 * scale;
            float W10 = pcx1 * pcy0 * scale;
            float W01 = pcx0 * pcy1 * scale;
            float W11 = pcx1 * pcy1 * scale;

            int o00 = (int)ybf * Ww + (int)xbf;

            #pragma unroll
            for (int j = 0; j < 8; j++) {
                const float* p = src + (size_t)j * HW + o00;
                float val = W00 * p[0] + W10 * p[1] + W01 * p[Ww] + W11 * p[Ww + 1];
                acc[j >> 2][d] += val * ref8[j];
            }
        }
    }

    #pragma unroll
    for (int g2 = 0; g2 < 2; g2++)
        #pragma unroll
        for (int d = 0; d < DD; d++)
            __builtin_nontemporal_store(acc[g2][d] * dn,
                &so_base[(size_t)(((c0 >> 2) + g2) * DD + d) * HW]);
}

extern "C" void kernel_launch(void* const* d_in, const int* in_sizes, int n_in,
                              void* d_out, int out_size, void* d_ws, size_t ws_size,
                              hipStream_t stream) {
    const float* depth_values   = (const float*)d_in[0];
    const float* features       = (const float*)d_in[1];
    const float* projm          = (const float*)d_in[2];
    const float* depth_interval = (const float*)d_in[3];
    const float* view_weights   = (const float*)d_in[6];

    float* out      = (float*)d_out;
    float* sim_out  = out;                              // (B, G*DD, H, W)
    float* samp_out = out + (size_t)Bn * GG * DD * HW;  // (B, DD, H, W)
    float* P12      = (float*)d_ws;                     // 16 x 12 floats

    proj_kernel<<<1, 64, 0, stream>>>(projm, P12);

    if (ws_size >= (size_t)FT_OFFSET + FT_BYTES) {
        float* ft = (float*)((char*)d_ws + FT_OFFSET);
        transpose_kernel<<<Bn * 4 * BLOCKS_PER_B, 256, 0, stream>>>(features, ft);
        cost_kernel_t<<<Bn * BLOCKS_PER_B, 256, 0, stream>>>(
            depth_values, features, ft, depth_interval, view_weights,
            P12, sim_out, samp_out);
    } else {
        cost_kernel_fb<<<Bn * NCHUNK * BLOCKS_PER_B, 256, 0, stream>>>(
            depth_values, features, depth_interval, view_weights,
            P12, sim_out, samp_out);
    }
}

// Round 7
// 494.127 us; speedup vs baseline: 1.4596x; 1.4596x over previous
//
#include <hip/hip_runtime.h>
#include <math.h>

#define Bn 4
#define Vn 5
#define Cc 32
#define Hh 256
#define Ww 320
#define DD 4
#define GG 8
#define HW (Hh*Ww)
#define BLOCKS_PER_B (HW/256)    // 320 pixel-blocks per image
#define NXCD 8
#define BAND (Bn * BLOCKS_PER_B / NXCD)   // 160 pixel-blocks per XCD band
#define NCHUNK 4

// ws layout: [0,768) P12 ; [1024, 1024+FT_BYTES) quad-interleaved features
// ftq[b][v][c/4][pix][4]  (one float4 = 4 channels of one pixel)
#define FT_OFFSET 1024
#define FT_BYTES ((size_t)Bn * 4 * 8 * HW * 4 * 4)

// ---------------------------------------------------------------------------
// Prologue 1: per (b, src_view i=1..4) compute P = src_proj_new @ inv(ref_proj_new)
// ---------------------------------------------------------------------------
__global__ void proj_kernel(const float* __restrict__ proj, float* __restrict__ out12) {
    int t = blockIdx.x * blockDim.x + threadIdx.x;
    if (t >= Bn * (Vn - 1)) return;
    int b = t / (Vn - 1);
    int i = t % (Vn - 1) + 1;

    const float* pb = proj + (size_t)b * Vn * 2 * 16;

    double refm[16], srcm[16];
    {
        const float* E = pb + 0 * 32 + 0;
        const float* K = pb + 0 * 32 + 16;
        for (int r = 0; r < 3; r++)
            for (int c = 0; c < 4; c++) {
                double s = 0.0;
                for (int k = 0; k < 3; k++) s += (double)K[r*4+k] * (double)E[k*4+c];
                refm[r*4+c] = s;
            }
        for (int c = 0; c < 4; c++) refm[12+c] = (double)E[12+c];
    }
    {
        const float* E = pb + i * 32 + 0;
        const float* K = pb + i * 32 + 16;
        for (int r = 0; r < 3; r++)
            for (int c = 0; c < 4; c++) {
                double s = 0.0;
                for (int k = 0; k < 3; k++) s += (double)K[r*4+k] * (double)E[k*4+c];
                srcm[r*4+c] = s;
            }
        for (int c = 0; c < 4; c++) srcm[12+c] = (double)E[12+c];
    }

    double a[16], inv[16];
    for (int k = 0; k < 16; k++) { a[k] = refm[k]; inv[k] = 0.0; }
    inv[0] = inv[5] = inv[10] = inv[15] = 1.0;
    for (int col = 0; col < 4; col++) {
        int piv = col; double best = fabs(a[col*4+col]);
        for (int r = col + 1; r < 4; r++) {
            double v = fabs(a[r*4+col]);
            if (v > best) { best = v; piv = r; }
        }
        if (piv != col) {
            for (int c = 0; c < 4; c++) {
                double tmp = a[col*4+c]; a[col*4+c] = a[piv*4+c]; a[piv*4+c] = tmp;
                tmp = inv[col*4+c]; inv[col*4+c] = inv[piv*4+c]; inv[piv*4+c] = tmp;
            }
        }
        double rd = 1.0 / a[col*4+col];
        for (int c = 0; c < 4; c++) { a[col*4+c] *= rd; inv[col*4+c] *= rd; }
        for (int r = 0; r < 4; r++) {
            if (r == col) continue;
            double f = a[r*4+col];
            for (int c = 0; c < 4; c++) { a[r*4+c] -= f * a[col*4+c]; inv[r*4+c] -= f * inv[col*4+c]; }
        }
    }

    double P[16];
    for (int r = 0; r < 4; r++)
        for (int c = 0; c < 4; c++) {
            double s = 0.0;
            for (int k = 0; k < 4; k++) s += srcm[r*4+k] * inv[k*4+c];
            P[r*4+c] = s;
        }

    float* o = out12 + t * 12;
    o[0] = (float)P[0];  o[1] = (float)P[1];  o[2]  = (float)P[2];
    o[3] = (float)P[4];  o[4] = (float)P[5];  o[5]  = (float)P[6];
    o[6] = (float)P[8];  o[7] = (float)P[9];  o[8]  = (float)P[10];
    o[9] = (float)P[3];  o[10] = (float)P[7]; o[11] = (float)P[11];
}

// ---------------------------------------------------------------------------
// Prologue 2: repack src views (v=1..4) to QUAD-interleaved:
//   ftq[b][v][q][pix][4], q = c/4.
// r6 lesson: full channel-last (128B/pixel) made every gather instruction
// touch ~64 cache lines. Quad granularity (16B/pixel/plane) keeps a wave's
// 64 lanes inside a ~1KB window (~8 lines/instr) while still serving 4
// channels per address. One thread per (b,v,pix): 32 coalesced strided
// reads -> 8 coalesced float4 stores into 8 quad planes.
// ---------------------------------------------------------------------------
__global__ __launch_bounds__(256) void transpose_kernel(
    const float* __restrict__ features, float* __restrict__ ft)
{
    int t   = blockIdx.x * 256 + threadIdx.x;   // 0 .. Bn*4*HW-1
    int b   = t / (4 * HW);
    int r   = t - b * 4 * HW;
    int v   = r / HW;                            // 0..3 -> src view v+1
    int pix = r - v * HW;

    const float* src = features + ((size_t)(b * Vn + (v + 1)) * Cc) * HW + pix;
    float4* dst = reinterpret_cast<float4*>(ft);

    #pragma unroll
    for (int q = 0; q < 8; q++) {
        float4 o;
        o.x = src[(size_t)(q * 4 + 0) * HW];
        o.y = src[(size_t)(q * 4 + 1) * HW];
        o.z = src[(size_t)(q * 4 + 2) * HW];
        o.w = src[(size_t)(q * 4 + 3) * HW];
        dst[((size_t)(b * 4 + v) * 8 + q) * HW + pix] = o;
    }
}

// ---------------------------------------------------------------------------
// Main kernel (quad path). Refined model after r0/r3/r5/r6:
//   * r0/r3/r5 invariant 17.6 cyc per gather wave-instr = TA ADDRESS rate
//     (64 addrs / 4 per cyc), lines nearly free because channel-first
//     gathers are wave-coalesced (~4 lines/instr).
//   * r6 (channel-last) cut instrs 4x but scattered to ~64 lines/instr and
//     blew VGPR to 168 -> slower. Address saving must preserve coalescing
//     and the lean register profile.
// Quad layout does both: per (i,d) per 8-ch chunk: 8 float4 gathers
// (2 quads x 4 corners) instead of 32 dwords; lanes stride 16B.
// Grid/banding/body = verified r5 (chunk-split, XCD banded, nontemporal).
// Loads are NAMED float4 scalars (no arrays -> no scratch; r4 lesson).
// Expected: gather instrs/CU 40960 -> 10240 -> TA floor ~68 us.
// ---------------------------------------------------------------------------
__global__ __launch_bounds__(256) void cost_kernel_q(
    const float* __restrict__ depth_values,
    const float* __restrict__ features,
    const float* __restrict__ ft,
    const float* __restrict__ depth_interval,
    const float* __restrict__ view_weights,
    const float* __restrict__ P12,
    float* __restrict__ sim_out,
    float* __restrict__ samp_out)
{
    int bid   = blockIdx.x;              // 0..5119
    int xcd   = bid & (NXCD - 1);
    int s     = bid >> 3;
    int pbb   = s >> 2;                  // 0..159 band-local pixel-block
    int chunk = s & 3;                   // 0..3 channel chunk (wave-uniform)
    int unit  = xcd * BAND + pbb;
    int b     = unit / BLOCKS_PER_B;     // wave-uniform
    int pb    = unit - b * BLOCKS_PER_B;
    int c0    = chunk * 8;
    int q0    = chunk * 2;               // first quad of this chunk

    int pix = pb * 256 + threadIdx.x;
    int h   = pix / Ww;
    int w   = pix - h * Ww;

    float inv_d = 1.0f / depth_values[b * HW + pix];
    float itv   = depth_interval[b * HW + pix];
    float dmin  = inv_d - 2.0f * itv;
    float step  = (4.0f * itv) / 3.0f;

    float depth[DD];
    #pragma unroll
    for (int d = 0; d < DD; d++) {
        float sdi = dmin + (float)d * step;
        depth[d] = 1.0f / sdi;
    }
    if (chunk == 0) {                    // samples written exactly once per (b,pix)
        #pragma unroll
        for (int d = 0; d < DD; d++)
            __builtin_nontemporal_store(depth[d],
                &samp_out[((size_t)b * DD + d) * HW + pix]);
    }

    float vw[Vn - 1];
    float wsum = 0.0f;
    #pragma unroll
    for (int i = 0; i < Vn - 1; i++) {
        vw[i] = view_weights[((size_t)b * (Vn - 1) + i) * HW + pix];
        wsum += vw[i];
    }
    float dn = 1.0f / (wsum + 1e-6f);

    const float xf = (float)w, yf = (float)h;
    const float* refp = features + (size_t)b * Vn * Cc * HW + pix;
    float* so_base = sim_out + (size_t)b * (GG * DD) * HW + pix;

    float ref8[8];
    #pragma unroll
    for (int j = 0; j < 8; j++) ref8[j] = refp[(size_t)(c0 + j) * HW];

    float acc[2][DD];
    #pragma unroll
    for (int g2 = 0; g2 < 2; g2++)
        #pragma unroll
        for (int d = 0; d < DD; d++) acc[g2][d] = 0.0f;

    const float4* ftq = reinterpret_cast<const float4*>(ft);

    #pragma unroll 1
    for (int i = 0; i < Vn - 1; i++) {
        const float* P = P12 + (b * (Vn - 1) + i) * 12;   // uniform -> s_load
        float rx = P[0] * xf + P[1] * yf + P[2];
        float ry = P[3] * xf + P[4] * yf + P[5];
        float rz = P[6] * xf + P[7] * yf + P[8];
        float tx = P[9], ty = P[10], tz = P[11];

        float scale = 0.25f * vw[i];
        // quad planes for this (b, src view i): planes (b*4+i)*8 + q
        const float4* plane0 = ftq + ((size_t)((b * 4 + i) * 8) + q0)     * HW;
        const float4* plane1 = ftq + ((size_t)((b * 4 + i) * 8) + q0 + 1) * HW;

        #pragma unroll
        for (int d = 0; d < DD; d++) {
            float D  = depth[d];
            float px = rx * D + tx;
            float py = ry * D + ty;
            float pz = rz * D + tz;
            float rpz = 1.0f / pz;
            float gx = px * rpz;
            float gy = py * rpz;

            float x0f = floorf(gx);
            float y0f = floorf(gy);
            float wx1 = gx - x0f;
            float wy1 = gy - y0f;
            float wx0 = 1.0f - wx1;
            float wy0 = 1.0f - wy1;

            float xbf = fminf(fmaxf(x0f, 0.0f), (float)(Ww - 2));
            float ybf = fminf(fmaxf(y0f, 0.0f), (float)(Hh - 2));
            float dxf = x0f - xbf;
            float dyf = y0f - ybf;

            float pcx0 = (dxf == 0.0f) ? wx0 : ((dxf == -1.0f) ? wx1 : 0.0f);
            float pcx1 = (dxf == 0.0f) ? wx1 : ((dxf ==  1.0f) ? wx0 : 0.0f);
            float pcy0 = (dyf == 0.0f) ? wy0 : ((dyf == -1.0f) ? wy1 : 0.0f);
            float pcy1 = (dyf == 0.0f) ? wy1 : ((dyf ==  1.0f) ? wy0 : 0.0f);

            float W00 = pcx0 * pcy0 * scale;
            float W10 = pcx1 * pcy0 * scale;
            float W01 = pcx0 * pcy1 * scale;
            float W11 = pcx1 * pcy1 * scale;

            int o00 = (int)ybf * Ww + (int)xbf;

            // ---- 8 named float4 gathers (no arrays -> no scratch) ----
            float4 A0 = plane0[o00];
            float4 B0 = plane0[o00 + 1];
            float4 C0 = plane0[o00 + Ww];
            float4 D0 = plane0[o00 + Ww + 1];
            float4 A1 = plane1[o00];
            float4 B1 = plane1[o00 + 1];
            float4 C1 = plane1[o00 + Ww];
            float4 D1 = plane1[o00 + Ww + 1];

            float v0 = W00 * A0.x + W10 * B0.x + W01 * C0.x + W11 * D0.x;
            float v1 = W00 * A0.y + W10 * B0.y + W01 * C0.y + W11 * D0.y;
            float v2 = W00 * A0.z + W10 * B0.z + W01 * C0.z + W11 * D0.z;
            float v3 = W00 * A0.w + W10 * B0.w + W01 * C0.w + W11 * D0.w;
            acc[0][d] += v0 * ref8[0] + v1 * ref8[1] + v2 * ref8[2] + v3 * ref8[3];

            float u0 = W00 * A1.x + W10 * B1.x + W01 * C1.x + W11 * D1.x;
            float u1 = W00 * A1.y + W10 * B1.y + W01 * C1.y + W11 * D1.y;
            float u2 = W00 * A1.z + W10 * B1.z + W01 * C1.z + W11 * D1.z;
            float u3 = W00 * A1.w + W10 * B1.w + W01 * C1.w + W11 * D1.w;
            acc[1][d] += u0 * ref8[4] + u1 * ref8[5] + u2 * ref8[6] + u3 * ref8[7];
        }
    }

    // similarity index k = g*DD + d, g = q0 + g2 (group == quad)
    #pragma unroll
    for (int g2 = 0; g2 < 2; g2++)
        #pragma unroll
        for (int d = 0; d < DD; d++)
            __builtin_nontemporal_store(acc[g2][d] * dn,
                &so_base[(size_t)((q0 + g2) * DD + d) * HW]);
}

// ---------------------------------------------------------------------------
// Fallback (= verified round-5 kernel, 300 us) when ws can't hold the repack.
// ---------------------------------------------------------------------------
__global__ __launch_bounds__(256) void cost_kernel_fb(
    const float* __restrict__ depth_values,
    const float* __restrict__ features,
    const float* __restrict__ depth_interval,
    const float* __restrict__ view_weights,
    const float* __restrict__ P12,
    float* __restrict__ sim_out,
    float* __restrict__ samp_out)
{
    int bid   = blockIdx.x;
    int xcd   = bid & (NXCD - 1);
    int s     = bid >> 3;
    int pbb   = s >> 2;
    int chunk = s & 3;
    int unit  = xcd * BAND + pbb;
    int b     = unit / BLOCKS_PER_B;
    int pb    = unit - b * BLOCKS_PER_B;
    int c0    = chunk * 8;

    int pix = pb * 256 + threadIdx.x;
    int h   = pix / Ww;
    int w   = pix - h * Ww;

    float inv_d = 1.0f / depth_values[b * HW + pix];
    float itv   = depth_interval[b * HW + pix];
    float dmin  = inv_d - 2.0f * itv;
    float step  = (4.0f * itv) / 3.0f;

    float depth[DD];
    #pragma unroll
    for (int d = 0; d < DD; d++) {
        float sdi = dmin + (float)d * step;
        depth[d] = 1.0f / sdi;
    }
    if (chunk == 0) {
        #pragma unroll
        for (int d = 0; d < DD; d++)
            __builtin_nontemporal_store(depth[d],
                &samp_out[((size_t)b * DD + d) * HW + pix]);
    }

    float vw[Vn - 1];
    float wsum = 0.0f;
    #pragma unroll
    for (int i = 0; i < Vn - 1; i++) {
        vw[i] = view_weights[((size_t)b * (Vn - 1) + i) * HW + pix];
        wsum += vw[i];
    }
    float dn = 1.0f / (wsum + 1e-6f);

    const float xf = (float)w, yf = (float)h;
    const float* refp = features + (size_t)b * Vn * Cc * HW + pix;
    float* so_base = sim_out + (size_t)b * (GG * DD) * HW + pix;

    float ref8[8];
    #pragma unroll
    for (int j = 0; j < 8; j++) ref8[j] = refp[(size_t)(c0 + j) * HW];

    float acc[2][DD];
    #pragma unroll
    for (int g2 = 0; g2 < 2; g2++)
        #pragma unroll
        for (int d = 0; d < DD; d++) acc[g2][d] = 0.0f;

    #pragma unroll 1
    for (int i = 0; i < Vn - 1; i++) {
        const float* P = P12 + (b * (Vn - 1) + i) * 12;
        float rx = P[0] * xf + P[1] * yf + P[2];
        float ry = P[3] * xf + P[4] * yf + P[5];
        float rz = P[6] * xf + P[7] * yf + P[8];
        float tx = P[9], ty = P[10], tz = P[11];

        float scale = 0.25f * vw[i];
        const float* src = features + ((size_t)(b * Vn) + (i + 1)) * Cc * HW
                         + (size_t)c0 * HW;

        #pragma unroll
        for (int d = 0; d < DD; d++) {
            float D  = depth[d];
            float px = rx * D + tx;
            float py = ry * D + ty;
            float pz = rz * D + tz;
            float rpz = 1.0f / pz;
            float gx = px * rpz;
            float gy = py * rpz;

            float x0f = floorf(gx);
            float y0f = floorf(gy);
            float wx1 = gx - x0f;
            float wy1 = gy - y0f;
            float wx0 = 1.0f - wx1;
            float wy0 = 1.0f - wy1;

            float xbf = fminf(fmaxf(x0f, 0.0f), (float)(Ww - 2));
            float ybf = fminf(fmaxf(y0f, 0.0f), (float)(Hh - 2));
            float dxf = x0f - xbf;
            float dyf = y0f - ybf;

            float pcx0 = (dxf == 0.0f) ? wx0 : ((dxf == -1.0f) ? wx1 : 0.0f);
            float pcx1 = (dxf == 0.0f) ? wx1 : ((dxf ==  1.0f) ? wx0 : 0.0f);
            float pcy0 = (dyf == 0.0f) ? wy0 : ((dyf == -1.0f) ? wy1 : 0.0f);
            float pcy1 = (dyf == 0.0f) ? wy1 : ((dyf ==  1.0f) ? wy0 : 0.0f);

            float W00 = pcx0 * pcy0 * scale;
            float W10 = pcx1 * pcy0 * scale;
            float W01 = pcx0 * pcy1 * scale;
            float W11 = pcx1 * pcy1 * scale;

            int o00 = (int)ybf * Ww + (int)xbf;

            #pragma unroll
            for (int j = 0; j < 8; j++) {
                const float* p = src + (size_t)j * HW + o00;
                float val = W00 * p[0] + W10 * p[1] + W01 * p[Ww] + W11 * p[Ww + 1];
                acc[j >> 2][d] += val * ref8[j];
            }
        }
    }

    #pragma unroll
    for (int g2 = 0; g2 < 2; g2++)
        #pragma unroll
        for (int d = 0; d < DD; d++)
            __builtin_nontemporal_store(acc[g2][d] * dn,
                &so_base[(size_t)(((c0 >> 2) + g2) * DD + d) * HW]);
}

extern "C" void kernel_launch(void* const* d_in, const int* in_sizes, int n_in,
                              void* d_out, int out_size, void* d_ws, size_t ws_size,
                              hipStream_t stream) {
    const float* depth_values   = (const float*)d_in[0];
    const float* features       = (const float*)d_in[1];
    const float* projm          = (const float*)d_in[2];
    const float* depth_interval = (const float*)d_in[3];
    const float* view_weights   = (const float*)d_in[6];

    float* out      = (float*)d_out;
    float* sim_out  = out;                              // (B, G*DD, H, W)
    float* samp_out = out + (size_t)Bn * GG * DD * HW;  // (B, DD, H, W)
    float* P12      = (float*)d_ws;                     // 16 x 12 floats

    proj_kernel<<<1, 64, 0, stream>>>(projm, P12);

    if (ws_size >= (size_t)FT_OFFSET + FT_BYTES) {
        float* ft = (float*)((char*)d_ws + FT_OFFSET);
        transpose_kernel<<<Bn * 4 * BLOCKS_PER_B, 256, 0, stream>>>(features, ft);
        cost_kernel_q<<<Bn * NCHUNK * BLOCKS_PER_B, 256, 0, stream>>>(
            depth_values, features, ft, depth_interval, view_weights,
            P12, sim_out, samp_out);
    } else {
        cost_kernel_fb<<<Bn * NCHUNK * BLOCKS_PER_B, 256, 0, stream>>>(
            depth_values, features, depth_interval, view_weights,
            P12, sim_out, samp_out);
    }
}